// Round 1
// baseline (2114.053 us; speedup 1.0000x reference)
//
#include <hip/hip_runtime.h>
#include <hip/hip_bf16.h>
#include <cstdint>

// Problem constants (match setup_inputs)
constexpr int B  = 2;
constexpr int L  = 2048;
constexpr int S  = 2048;
constexpr int DM = 1024;
constexpr int H  = 16;
constexpr int R  = 32;     // rank
constexpr int DH = 64;     // head dim
constexpr int TOPK = 32;
constexpr float SCALE = 0.17677669529663687f; // 1/sqrt(32)

// ---------------------------------------------------------------------------
// Tiled fp32 GEMM: C[M,N] = A[M,K] @ W[K,N] + bias[N]
// BM=BN=128, BK=16, 256 threads, 8x8 microtile.
// M,N,K must be multiples of 128/128/16 (true here: M=4096, N in {512,1024}, K=1024).
// ---------------------------------------------------------------------------
__global__ __launch_bounds__(256, 2)
void gemm128_f32(const float* __restrict__ A, const float* __restrict__ W,
                 const float* __restrict__ bias, float* __restrict__ C,
                 int M, int N, int K)
{
    __shared__ float As[16][136];  // [kk][row], 136*4=544B = 34*16B (16B-aligned rows)
    __shared__ float Ws[16][132];  // [kk][col], 132*4=528B = 33*16B

    const int t  = threadIdx.x;
    const int tx = t & 15;
    const int ty = t >> 4;
    const int m0 = blockIdx.y * 128;
    const int n0 = blockIdx.x * 128;

    float acc[8][8];
#pragma unroll
    for (int i = 0; i < 8; ++i)
#pragma unroll
        for (int j = 0; j < 8; ++j) acc[i][j] = 0.f;

    for (int kb = 0; kb < K; kb += 16) {
        __syncthreads();
        // stage A tile (128 rows x 16 k) transposed -> As[kk][row]
#pragma unroll
        for (int it = 0; it < 2; ++it) {
            int f4  = t + it * 256;        // 0..511
            int row = f4 >> 2;
            int cg  = (f4 & 3) * 4;
            float4 av = *(const float4*)&A[(size_t)(m0 + row) * K + kb + cg];
            As[cg + 0][row] = av.x;
            As[cg + 1][row] = av.y;
            As[cg + 2][row] = av.z;
            As[cg + 3][row] = av.w;
        }
        // stage W tile (16 k x 128 cols) -> Ws[kk][col]
#pragma unroll
        for (int it = 0; it < 2; ++it) {
            int f4 = t + it * 256;
            int kk = f4 >> 5;
            int cb = (f4 & 31) * 4;
            *(float4*)&Ws[kk][cb] = *(const float4*)&W[(size_t)(kb + kk) * N + n0 + cb];
        }
        __syncthreads();
#pragma unroll
        for (int kk = 0; kk < 16; ++kk) {
            float a[8], w[8];
#pragma unroll
            for (int i = 0; i < 8; ++i) a[i] = As[kk][ty * 8 + i];
#pragma unroll
            for (int j = 0; j < 8; ++j) w[j] = Ws[kk][tx * 8 + j];
#pragma unroll
            for (int i = 0; i < 8; ++i)
#pragma unroll
                for (int j = 0; j < 8; ++j)
                    acc[i][j] = fmaf(a[i], w[j], acc[i][j]);
        }
    }

    float4 b0 = *(const float4*)&bias[n0 + tx * 8];
    float4 b1 = *(const float4*)&bias[n0 + tx * 8 + 4];
#pragma unroll
    for (int i = 0; i < 8; ++i) {
        float4 o0 = make_float4(acc[i][0] + b0.x, acc[i][1] + b0.y,
                                acc[i][2] + b0.z, acc[i][3] + b0.w);
        float4 o1 = make_float4(acc[i][4] + b1.x, acc[i][5] + b1.y,
                                acc[i][6] + b1.z, acc[i][7] + b1.w);
        size_t off = (size_t)(m0 + ty * 8 + i) * N + n0 + tx * 8;
        *(float4*)&C[off]     = o0;
        *(float4*)&C[off + 4] = o1;
    }
}

// ---------------------------------------------------------------------------
// Fused top-k sparse attention.
// Grid: (L/16, H, B). Block: 256 threads = 4 waves; each wave owns 4 query rows.
// Per block: stage K (for this b,h) transposed in LDS in 4 chunks of 512;
// scores live in registers (sc[4][32] per lane; lane owns s = c*512+i*64+lane).
// Exact 32nd-largest via MSB radix select on sortable-uint with ballot counts.
// Sparse PV gather over the selected ~32 indices.
// ---------------------------------------------------------------------------
__global__ __launch_bounds__(256, 2)
void attn_topk_sparse(const float* __restrict__ Qp, const float* __restrict__ Kp,
                      const float* __restrict__ Vp, float* __restrict__ Oh)
{
    __shared__ float Klds[32][512];   // [r][s_local]  64 KB
    __shared__ float Qlds[16][32];    // 2 KB (pre-scaled by 1/sqrt(R))
    __shared__ int   slist[16][64];   // selected s indices per row
    __shared__ float swt[16][64];     // normalized softmax weights per row
    __shared__ int   scount[16];

    const int t    = threadIdx.x;
    const int lane = t & 63;
    const int wv   = t >> 6;
    const int b    = blockIdx.z;
    const int h    = blockIdx.y;
    const int lbase = blockIdx.x * 16;
    const int wr0  = wv * 4;

    // stage Q tile (16 rows x 32), pre-scaled
    if (t < 128) {
        int row = t >> 3, rg = (t & 7) * 4;
        float4 qv = *(const float4*)&Qp[(size_t)(b * L + lbase + row) * (H * R) + h * R + rg];
        Qlds[row][rg + 0] = qv.x * SCALE;
        Qlds[row][rg + 1] = qv.y * SCALE;
        Qlds[row][rg + 2] = qv.z * SCALE;
        Qlds[row][rg + 3] = qv.w * SCALE;
    }
    if (t < 16) scount[t] = 0;

    float sc[4][32];
#pragma unroll
    for (int rr = 0; rr < 4; ++rr)
#pragma unroll
        for (int j = 0; j < 32; ++j) sc[rr][j] = 0.f;

    // ---- score phase: 4 chunks of 512 keys ----
#pragma unroll
    for (int c = 0; c < 4; ++c) {
        __syncthreads();
        // stage K chunk transposed: Klds[r][s_local]
#pragma unroll
        for (int it = 0; it < 16; ++it) {
            int fid = t + it * 256;         // 0..4095
            int sl  = fid >> 3;             // 0..511
            int rg  = (fid & 7) * 4;        // 0,4,..,28
            float4 kv = *(const float4*)&Kp[(size_t)(b * S + c * 512 + sl) * (H * R) + h * R + rg];
            Klds[rg + 0][sl] = kv.x;
            Klds[rg + 1][sl] = kv.y;
            Klds[rg + 2][sl] = kv.z;
            Klds[rg + 3][sl] = kv.w;
        }
        __syncthreads();
#pragma unroll
        for (int r = 0; r < 32; ++r) {
            float q0 = Qlds[wr0 + 0][r];
            float q1 = Qlds[wr0 + 1][r];
            float q2 = Qlds[wr0 + 2][r];
            float q3 = Qlds[wr0 + 3][r];
#pragma unroll
            for (int i = 0; i < 8; ++i) {
                float kv = Klds[r][i * 64 + lane];
                sc[0][c * 8 + i] = fmaf(q0, kv, sc[0][c * 8 + i]);
                sc[1][c * 8 + i] = fmaf(q1, kv, sc[1][c * 8 + i]);
                sc[2][c * 8 + i] = fmaf(q2, kv, sc[2][c * 8 + i]);
                sc[3][c * 8 + i] = fmaf(q3, kv, sc[3][c * 8 + i]);
            }
        }
    }

    // ---- per-row exact top-k selection + softmax + emit ----
#pragma unroll
    for (int rr = 0; rr < 4; ++rr) {
        // sortable-uint conversion (monotone bijection with float order)
        unsigned int u[32];
#pragma unroll
        for (int j = 0; j < 32; ++j) {
            unsigned int bb  = __float_as_uint(sc[rr][j]);
            unsigned int sgn = (unsigned int)(((int)bb) >> 31);
            u[j] = bb ^ (sgn | 0x80000000u);
        }
        // MSB radix select: P = max{T : count(u >= T) >= TOPK}  == kth-largest u
        unsigned int P = 0;
        for (int bit = 31; bit >= 0; --bit) {
            unsigned int test = P | (1u << bit);
            int cnt = 0;
#pragma unroll
            for (int j = 0; j < 32; ++j)
                cnt += (int)__popcll(__ballot(u[j] >= test));
            if (cnt >= TOPK) P = test;
        }
        // threshold back to float domain (matches reference's float >= compare)
        unsigned int tb = (P & 0x80000000u) ? (P ^ 0x80000000u) : ~P;
        float thr = __uint_as_float(tb);

        // row max (global max is always selected)
        float mx = -3.4e38f;
#pragma unroll
        for (int j = 0; j < 32; ++j) mx = fmaxf(mx, sc[rr][j]);
#pragma unroll
        for (int off = 32; off >= 1; off >>= 1)
            mx = fmaxf(mx, __shfl_xor(mx, off, 64));

        // softmax denominator over selected
        float dsum = 0.f;
#pragma unroll
        for (int j = 0; j < 32; ++j) {
            float e = __expf(sc[rr][j] - mx);
            dsum += (sc[rr][j] >= thr) ? e : 0.f;
        }
#pragma unroll
        for (int off = 32; off >= 1; off >>= 1)
            dsum += __shfl_xor(dsum, off, 64);
        float inv = 1.0f / dsum;

        // emit selected (index, normalized weight) lists
        int row = wr0 + rr;
#pragma unroll
        for (int j = 0; j < 32; ++j) {
            if (sc[rr][j] >= thr) {
                int pos = atomicAdd(&scount[row], 1);
                if (pos < 64) {
                    slist[row][pos] = (j >> 3) * 512 + (j & 7) * 64 + lane;
                    swt[row][pos]   = __expf(sc[rr][j] - mx) * inv;
                }
            }
        }
    }
    asm volatile("s_waitcnt lgkmcnt(0)" ::: "memory");

    // ---- sparse PV: lane = output dim d (DH == 64 == wave size) ----
#pragma unroll
    for (int rr = 0; rr < 4; ++rr) {
        int row = wr0 + rr;
        int cnt = scount[row];
        cnt = cnt < 64 ? cnt : 64;
        float acc = 0.f;
        const float* vb = Vp + (size_t)b * S * DM + h * DH + lane;
        for (int tt = 0; tt < cnt; ++tt) {
            int   s = slist[row][tt];
            float w = swt[row][tt];
            acc = fmaf(w, vb[(size_t)s * DM], acc);
        }
        Oh[(size_t)(b * L + lbase + row) * DM + h * DH + lane] = acc;
    }
}

// ---------------------------------------------------------------------------
extern "C" void kernel_launch(void* const* d_in, const int* in_sizes, int n_in,
                              void* d_out, int out_size, void* d_ws, size_t ws_size,
                              hipStream_t stream)
{
    const float* q  = (const float*)d_in[0];
    const float* k  = (const float*)d_in[1];
    const float* v  = (const float*)d_in[2];
    const float* Wq = (const float*)d_in[3];
    const float* bq = (const float*)d_in[4];
    const float* Wk = (const float*)d_in[5];
    const float* bk = (const float*)d_in[6];
    const float* Wv = (const float*)d_in[7];
    const float* bv = (const float*)d_in[8];
    const float* Wo = (const float*)d_in[9];
    const float* bo = (const float*)d_in[10];
    // d_in[11] = pos_bias: per-head additive constant -> top-k and softmax are
    // invariant to it -> mathematically a no-op; skipped.

    float* out = (float*)d_out;
    char*  ws  = (char*)d_ws;

    // workspace layout (48 MiB total)
    float* Qp = (float*)(ws);                          //  8 MiB: (B*L, 512)
    float* Kp = (float*)(ws + (size_t)8  * 1024 * 1024); //  8 MiB: (B*S, 512)
    float* Vp = (float*)(ws + (size_t)16 * 1024 * 1024); // 16 MiB: (B*S, 1024)
    float* Oh = (float*)(ws + (size_t)32 * 1024 * 1024); // 16 MiB: (B*L, 1024)

    const int M = B * L;  // 4096
    dim3 blk(256);

    gemm128_f32<<<dim3((H * R) / 128, M / 128), blk, 0, stream>>>(q, Wq, bq, Qp, M, H * R, DM);
    gemm128_f32<<<dim3((H * R) / 128, M / 128), blk, 0, stream>>>(k, Wk, bk, Kp, M, H * R, DM);
    gemm128_f32<<<dim3(DM / 128, M / 128),      blk, 0, stream>>>(v, Wv, bv, Vp, M, DM, DM);

    attn_topk_sparse<<<dim3(L / 16, H, B), blk, 0, stream>>>(Qp, Kp, Vp, Oh);

    gemm128_f32<<<dim3(DM / 128, M / 128),      blk, 0, stream>>>(Oh, Wo, bo, out, M, DM, DM);
}

// Round 2
// 1534.033 us; speedup vs baseline: 1.3781x; 1.3781x over previous
//
#include <hip/hip_runtime.h>
#include <hip/hip_bf16.h>
#include <cstdint>

// Problem constants (match setup_inputs)
constexpr int B  = 2;
constexpr int L  = 2048;
constexpr int S  = 2048;
constexpr int DM = 1024;
constexpr int H  = 16;
constexpr int R  = 32;     // rank
constexpr int DH = 64;     // head dim
constexpr int TOPK = 32;
constexpr float SCALE = 0.17677669529663687f; // 1/sqrt(32)

// ---------------------------------------------------------------------------
// Tiled fp32 GEMM: C[M,N] = A[M,K] @ W[K,N] + bias[N]   (unchanged from R1)
// ---------------------------------------------------------------------------
__global__ __launch_bounds__(256, 2)
void gemm128_f32(const float* __restrict__ A, const float* __restrict__ W,
                 const float* __restrict__ bias, float* __restrict__ C,
                 int M, int N, int K)
{
    __shared__ float As[16][136];
    __shared__ float Ws[16][132];

    const int t  = threadIdx.x;
    const int tx = t & 15;
    const int ty = t >> 4;
    const int m0 = blockIdx.y * 128;
    const int n0 = blockIdx.x * 128;

    float acc[8][8];
#pragma unroll
    for (int i = 0; i < 8; ++i)
#pragma unroll
        for (int j = 0; j < 8; ++j) acc[i][j] = 0.f;

    for (int kb = 0; kb < K; kb += 16) {
        __syncthreads();
#pragma unroll
        for (int it = 0; it < 2; ++it) {
            int f4  = t + it * 256;
            int row = f4 >> 2;
            int cg  = (f4 & 3) * 4;
            float4 av = *(const float4*)&A[(size_t)(m0 + row) * K + kb + cg];
            As[cg + 0][row] = av.x;
            As[cg + 1][row] = av.y;
            As[cg + 2][row] = av.z;
            As[cg + 3][row] = av.w;
        }
#pragma unroll
        for (int it = 0; it < 2; ++it) {
            int f4 = t + it * 256;
            int kk = f4 >> 5;
            int cb = (f4 & 31) * 4;
            *(float4*)&Ws[kk][cb] = *(const float4*)&W[(size_t)(kb + kk) * N + n0 + cb];
        }
        __syncthreads();
#pragma unroll
        for (int kk = 0; kk < 16; ++kk) {
            float a[8], w[8];
#pragma unroll
            for (int i = 0; i < 8; ++i) a[i] = As[kk][ty * 8 + i];
#pragma unroll
            for (int j = 0; j < 8; ++j) w[j] = Ws[kk][tx * 8 + j];
#pragma unroll
            for (int i = 0; i < 8; ++i)
#pragma unroll
                for (int j = 0; j < 8; ++j)
                    acc[i][j] = fmaf(a[i], w[j], acc[i][j]);
        }
    }

    float4 b0 = *(const float4*)&bias[n0 + tx * 8];
    float4 b1 = *(const float4*)&bias[n0 + tx * 8 + 4];
#pragma unroll
    for (int i = 0; i < 8; ++i) {
        float4 o0 = make_float4(acc[i][0] + b0.x, acc[i][1] + b0.y,
                                acc[i][2] + b0.z, acc[i][3] + b0.w);
        float4 o1 = make_float4(acc[i][4] + b1.x, acc[i][5] + b1.y,
                                acc[i][6] + b1.z, acc[i][7] + b1.w);
        size_t off = (size_t)(m0 + ty * 8 + i) * N + n0 + tx * 8;
        *(float4*)&C[off]     = o0;
        *(float4*)&C[off + 4] = o1;
    }
}

// ---------------------------------------------------------------------------
// Fused top-k sparse attention, v2.
// Grid: 4096 1-D blocks (XCD-swizzled), 256 threads = 4 waves, 4 rows/wave.
// K chunk = 256 keys in XOR-swizzled float4 LDS (32 KB) -> 4 blocks/CU.
// Scores in registers sc[4][32] (lane owns key s = c*256 + i*64 + lane).
// Early-exit MSB radix select; ballot-prefix compaction; single exp pass;
// PV normalizes once at the end.
// ---------------------------------------------------------------------------
__global__ __launch_bounds__(256)
void attn_topk_sparse(const float* __restrict__ Qp, const float* __restrict__ Kp,
                      const float* __restrict__ Vp, float* __restrict__ Oh)
{
    __shared__ float4 Kq[2048];              // 32 KB: 256 keys x 8 quads, XOR-swizzled
    __shared__ float  Qlds[16][32];          // 2 KB, pre-scaled
    __shared__ unsigned short slist[16][40]; // selected key index per row
    __shared__ float  swt[16][40];           // unnormalized exp weights per row

    const int t    = threadIdx.x;
    const int lane = t & 63;
    const int wv   = t >> 6;
    const int wr0  = wv * 4;

    // XCD-aware swizzle: all 128 tiles of one (b,h) land on one XCD (wgid%8)
    const int wgid = blockIdx.x;
    const int xcd  = wgid & 7;
    const int jj   = wgid >> 3;              // 0..511
    const int bh   = xcd + 8 * (jj >> 7);    // 0..31
    const int tile = jj & 127;
    const int b    = bh >> 4;
    const int h    = bh & 15;
    const int lbase = tile * 16;

    // stage Q tile (16 rows x 32), pre-scaled
    if (t < 128) {
        int row = t >> 3, rg = (t & 7) * 4;
        float4 qv = *(const float4*)&Qp[(size_t)(b * L + lbase + row) * (H * R) + h * R + rg];
        Qlds[row][rg + 0] = qv.x * SCALE;
        Qlds[row][rg + 1] = qv.y * SCALE;
        Qlds[row][rg + 2] = qv.z * SCALE;
        Qlds[row][rg + 3] = qv.w * SCALE;
    }

    float sc[4][32];
#pragma unroll
    for (int rr = 0; rr < 4; ++rr)
#pragma unroll
        for (int j = 0; j < 32; ++j) sc[rr][j] = 0.f;

    const int sx = lane & 7;

    // ---- score phase: 8 chunks of 256 keys ----
    for (int c = 0; c < 8; ++c) {
        __syncthreads();
        // stage K chunk: key sl's quad qg -> Kq[sl*8 + (qg ^ (sl&7))]
#pragma unroll
        for (int it = 0; it < 8; ++it) {
            int fid = t + it * 256;          // 0..2047
            int sl  = fid >> 3;              // key 0..255
            int qg  = fid & 7;               // quad 0..7
            float4 kv = *(const float4*)&Kp[(size_t)(b * S + c * 256 + sl) * (H * R) + h * R + qg * 4];
            Kq[sl * 8 + (qg ^ (sl & 7))] = kv;
        }
        __syncthreads();
#pragma unroll
        for (int q = 0; q < 8; ++q) {
            float4 q0 = *(const float4*)&Qlds[wr0 + 0][q * 4];
            float4 q1 = *(const float4*)&Qlds[wr0 + 1][q * 4];
            float4 q2 = *(const float4*)&Qlds[wr0 + 2][q * 4];
            float4 q3 = *(const float4*)&Qlds[wr0 + 3][q * 4];
#pragma unroll
            for (int i = 0; i < 4; ++i) {
                float4 kf = Kq[(i * 64 + lane) * 8 + (q ^ sx)];
                int idx = c * 4 + i;
                sc[0][idx] = fmaf(q0.x, kf.x, sc[0][idx]);
                sc[0][idx] = fmaf(q0.y, kf.y, sc[0][idx]);
                sc[0][idx] = fmaf(q0.z, kf.z, sc[0][idx]);
                sc[0][idx] = fmaf(q0.w, kf.w, sc[0][idx]);
                sc[1][idx] = fmaf(q1.x, kf.x, sc[1][idx]);
                sc[1][idx] = fmaf(q1.y, kf.y, sc[1][idx]);
                sc[1][idx] = fmaf(q1.z, kf.z, sc[1][idx]);
                sc[1][idx] = fmaf(q1.w, kf.w, sc[1][idx]);
                sc[2][idx] = fmaf(q2.x, kf.x, sc[2][idx]);
                sc[2][idx] = fmaf(q2.y, kf.y, sc[2][idx]);
                sc[2][idx] = fmaf(q2.z, kf.z, sc[2][idx]);
                sc[2][idx] = fmaf(q2.w, kf.w, sc[2][idx]);
                sc[3][idx] = fmaf(q3.x, kf.x, sc[3][idx]);
                sc[3][idx] = fmaf(q3.y, kf.y, sc[3][idx]);
                sc[3][idx] = fmaf(q3.z, kf.z, sc[3][idx]);
                sc[3][idx] = fmaf(q3.w, kf.w, sc[3][idx]);
            }
        }
    }

    // ---- per-row exact top-k selection + softmax weights ----
    int   cnts[4];
    float invs[4];
    const unsigned long long lanelt = (1ull << lane) - 1ull;

#pragma unroll
    for (int rr = 0; rr < 4; ++rr) {
        const int row = wr0 + rr;

        // row max (float domain)
        float mx = sc[rr][0];
#pragma unroll
        for (int j = 1; j < 32; ++j) mx = fmaxf(mx, sc[rr][j]);
#pragma unroll
        for (int off = 32; off >= 1; off >>= 1)
            mx = fmaxf(mx, __shfl_xor(mx, off, 64));

        // in-place sortable-uint conversion (monotone bijection)
#pragma unroll
        for (int j = 0; j < 32; ++j) {
            unsigned int bb  = __float_as_uint(sc[rr][j]);
            unsigned int sgn = (unsigned int)(((int)bb) >> 31);
            sc[rr][j] = __uint_as_float(bb ^ (sgn | 0x80000000u));
        }

        // MSB radix select with exact-count early exit:
        // P ends as a threshold with |{u >= P}| == TOPK (or == kth-largest on full run)
        unsigned int P = 0;
        int cnt = 0;
        for (int bit = 31; bit >= 0; --bit) {
            unsigned int test = P | (1u << bit);
            int c2 = 0;
#pragma unroll
            for (int j = 0; j < 32; ++j)
                c2 += (int)__popcll(__ballot(__float_as_uint(sc[rr][j]) >= test));
            if (c2 >= TOPK) {
                P = test;
                cnt = c2;
                if (c2 == TOPK) break;
            }
        }

        // single exp pass: emit (idx, unnormalized weight) + denominator
        float dsum = 0.f;
        int   base = 0;
#pragma unroll
        for (int j = 0; j < 32; ++j) {
            unsigned int u = __float_as_uint(sc[rr][j]);
            bool sel = (u >= P);
            // invert sortable mapping
            unsigned int sg2  = (unsigned int)(((int)u) >> 31);
            unsigned int mask = 0x80000000u | ~sg2;
            float forig = __uint_as_float(u ^ mask);
            float e = __expf(forig - mx);
            unsigned long long m = __ballot(sel);
            if (sel) {
                int pos = base + (int)__popcll(m & lanelt);
                if (pos < 40) {
                    slist[row][pos] = (unsigned short)((j >> 2) * 256 + (j & 3) * 64 + lane);
                    swt[row][pos]   = e;
                }
            }
            dsum += sel ? e : 0.f;
            base += (int)__popcll(m);
        }
#pragma unroll
        for (int off = 32; off >= 1; off >>= 1)
            dsum += __shfl_xor(dsum, off, 64);
        invs[rr] = 1.0f / dsum;
        cnts[rr] = base < 40 ? base : 40;
    }

    asm volatile("s_waitcnt lgkmcnt(0)" ::: "memory");

    // ---- sparse PV: lane = output dim d (DH == 64 == wave size) ----
#pragma unroll
    for (int rr = 0; rr < 4; ++rr) {
        const int row = wr0 + rr;
        const int cn  = cnts[rr];
        const float* vb = Vp + (size_t)b * S * DM + h * DH + lane;
        float a0 = 0.f, a1 = 0.f, a2 = 0.f, a3 = 0.f;
        int tt = 0;
        for (; tt + 4 <= cn; tt += 4) {
            int   s0 = slist[row][tt + 0], s1 = slist[row][tt + 1];
            int   s2 = slist[row][tt + 2], s3 = slist[row][tt + 3];
            float w0 = swt[row][tt + 0],   w1 = swt[row][tt + 1];
            float w2 = swt[row][tt + 2],   w3 = swt[row][tt + 3];
            a0 = fmaf(w0, vb[(size_t)s0 * DM], a0);
            a1 = fmaf(w1, vb[(size_t)s1 * DM], a1);
            a2 = fmaf(w2, vb[(size_t)s2 * DM], a2);
            a3 = fmaf(w3, vb[(size_t)s3 * DM], a3);
        }
        for (; tt < cn; ++tt) {
            int s0 = slist[row][tt];
            a0 = fmaf(swt[row][tt], vb[(size_t)s0 * DM], a0);
        }
        Oh[(size_t)(b * L + lbase + row) * DM + h * DH + lane] =
            ((a0 + a1) + (a2 + a3)) * invs[rr];
    }
}

// ---------------------------------------------------------------------------
extern "C" void kernel_launch(void* const* d_in, const int* in_sizes, int n_in,
                              void* d_out, int out_size, void* d_ws, size_t ws_size,
                              hipStream_t stream)
{
    const float* q  = (const float*)d_in[0];
    const float* k  = (const float*)d_in[1];
    const float* v  = (const float*)d_in[2];
    const float* Wq = (const float*)d_in[3];
    const float* bq = (const float*)d_in[4];
    const float* Wk = (const float*)d_in[5];
    const float* bk = (const float*)d_in[6];
    const float* Wv = (const float*)d_in[7];
    const float* bv = (const float*)d_in[8];
    const float* Wo = (const float*)d_in[9];
    const float* bo = (const float*)d_in[10];
    // d_in[11] = pos_bias: per-head additive constant -> top-k/softmax invariant -> no-op.

    float* out = (float*)d_out;
    char*  ws  = (char*)d_ws;

    float* Qp = (float*)(ws);                            //  8 MiB: (B*L, 512)
    float* Kp = (float*)(ws + (size_t)8  * 1024 * 1024); //  8 MiB: (B*S, 512)
    float* Vp = (float*)(ws + (size_t)16 * 1024 * 1024); // 16 MiB: (B*S, 1024)
    float* Oh = (float*)(ws + (size_t)32 * 1024 * 1024); // 16 MiB: (B*L, 1024)

    const int M = B * L;  // 4096
    dim3 blk(256);

    gemm128_f32<<<dim3((H * R) / 128, M / 128), blk, 0, stream>>>(q, Wq, bq, Qp, M, H * R, DM);
    gemm128_f32<<<dim3((H * R) / 128, M / 128), blk, 0, stream>>>(k, Wk, bk, Kp, M, H * R, DM);
    gemm128_f32<<<dim3(DM / 128, M / 128),      blk, 0, stream>>>(v, Wv, bv, Vp, M, DM, DM);

    attn_topk_sparse<<<dim3(4096), blk, 0, stream>>>(Qp, Kp, Vp, Oh);

    gemm128_f32<<<dim3(DM / 128, M / 128),      blk, 0, stream>>>(Oh, Wo, bo, out, M, DM, DM);
}